// Round 10
// baseline (726.607 us; speedup 1.0000x reference)
//
#include <hip/hip_runtime.h>
#include <hip/hip_bf16.h>
#include <cstdint>
#include <cstddef>

#define N_NODES 32768
#define N_EDGES 262144
#define BGRAPH  32
#define NPG     1024
#define KSEL    820
#define NEG     0.2f

typedef unsigned short u16;
typedef __attribute__((ext_vector_type(4))) float f32x4;
typedef __attribute__((ext_vector_type(8))) short s16x8;

static __device__ __forceinline__ u16 f2bf(float v) {
    __hip_bfloat16 b(v);
    return *reinterpret_cast<u16*>(&b);
}
static __device__ __forceinline__ float bf2f(u16 u) {
    __hip_bfloat16 b = *reinterpret_cast<__hip_bfloat16*>(&u);
    return (float)b;
}

typedef const __attribute__((address_space(1))) void* gas_p;
typedef __attribute__((address_space(3))) void* las_p;
static __device__ __forceinline__ void gload16(const void* g, void* l) {
    __builtin_amdgcn_global_load_lds((gas_p)g, (las_p)l, 16, 0, 0);
}

// ---------------------------------------------------------------------------
// Prep: split x into bf16 hi/lo (x = hi + lo + eps, eps ~ 2^-16 rel)
// ---------------------------------------------------------------------------
__global__ __launch_bounds__(256) void k_split_x(
    const float* __restrict__ x, u16* __restrict__ xhi, u16* __restrict__ xlo)
{
    const int i = blockIdx.x * 256 + threadIdx.x;      // one float4 per thread
    const float4 v = *(const float4*)&x[(size_t)i * 4];
    u16 h0 = f2bf(v.x), h1 = f2bf(v.y), h2 = f2bf(v.z), h3 = f2bf(v.w);
    u16 l0 = f2bf(v.x - bf2f(h0));
    u16 l1 = f2bf(v.y - bf2f(h1));
    u16 l2 = f2bf(v.z - bf2f(h2));
    u16 l3 = f2bf(v.w - bf2f(h3));
    *(ushort4*)&xhi[(size_t)i * 4] = make_ushort4(h0, h1, h2, h3);
    *(ushort4*)&xlo[(size_t)i * 4] = make_ushort4(l0, l1, l2, l3);
}

// ---------------------------------------------------------------------------
// Prep: packed transposed B' [1024 n][512 k'] bf16: k'<256 hi(W[k']),
// k'>=256 lo(W[k'-256]). n<512 -> Wl, else Wr.
// ---------------------------------------------------------------------------
__global__ __launch_bounds__(256) void k_pack_bt(
    const float* __restrict__ Wl, const float* __restrict__ Wr,
    u16* __restrict__ BpT)
{
    const int kp = blockIdx.x * 256 + threadIdx.x;     // 0..511 (grid.x = 2)
    const int n  = blockIdx.y;                         // 0..1023
    const float* W = (n < 512) ? Wl : Wr;
    const int col = n & 511;
    const int k = kp & 255;
    const float v = W[(size_t)k * 512 + col];
    const u16 h = f2bf(v);
    const u16 o = (kp >= 256) ? f2bf(v - bf2f(h)) : h;
    BpT[(size_t)n * 512 + kp] = o;
}

// ---------------------------------------------------------------------------
// Prep: webf[slab][ch 128][32] bf16 = We[k][slab*128+ch] transposed (plain).
// ---------------------------------------------------------------------------
__global__ __launch_bounds__(256) void k_prep_we(
    const float* __restrict__ We, u16* __restrict__ webf)
{
    const int g = blockIdx.x * 256 + threadIdx.x;      // 0..16383 (64 blocks)
    const int slab = g >> 12, ch = (g >> 5) & 127, kk = g & 31;
    webf[g] = f2bf(We[(size_t)kk * 512 + slab * 128 + ch]);
}

// ---------------------------------------------------------------------------
// Prep: eabf[pos][32] bf16 = ea[sorted_eid[pos]][k] (plain sorted gather).
// ---------------------------------------------------------------------------
__global__ __launch_bounds__(256) void k_prep_ea(
    const float* __restrict__ ea, const int* __restrict__ sorted_eid,
    u16* __restrict__ eabf)
{
    const int g = blockIdx.x * 256 + threadIdx.x;      // E*32 elements
    const int pos = g >> 5, kk = g & 31;
    eabf[g] = f2bf(ea[(size_t)sorted_eid[pos] * 32 + kk]);
}

// ---------------------------------------------------------------------------
// Split-bf16 MFMA GEMM (unchanged from round 9).
// ---------------------------------------------------------------------------
__global__ __launch_bounds__(256) void gemm_mfma(
    const u16* __restrict__ xhi, const u16* __restrict__ xlo,
    const u16* __restrict__ BpT,
    const float* __restrict__ bl, const float* __restrict__ br,
    float* __restrict__ xl, float* __restrict__ xr)
{
    __shared__ u16 Ahs[128 * 32];
    __shared__ u16 Als[128 * 32];
    __shared__ u16 Bhs[128 * 32];
    __shared__ u16 Bls[128 * 32];

    const int raw = blockIdx.x;
    const int swz = (raw & 7) * 256 + (raw >> 3);
    const int mt = swz & 255, nt = swz >> 8;
    const int m0 = mt * 128, n0 = nt * 128;

    const int tid  = threadIdx.x;
    const int lane = tid & 63;
    const int wid  = tid >> 6;
    const int wr   = wid >> 1, wc = wid & 1;
    const int lr   = lane & 15;
    const int lk   = lane >> 4;

    f32x4 acc[4][4] = {};

    for (int q = 0; q < 8; ++q) {
        __syncthreads();
#pragma unroll
        for (int half = 0; half < 2; ++half) {
            const int w   = half * 256 + tid;
            const int row = w >> 2, cc = w & 3;
            const int cs  = cc ^ (row & 3) ^ ((row >> 2) & 3);
            const int ko  = q * 32 + cs * 8;
            gload16(&xhi[(size_t)(m0 + row) * 256 + ko],       &Ahs[w * 8]);
            gload16(&xlo[(size_t)(m0 + row) * 256 + ko],       &Als[w * 8]);
            gload16(&BpT[(size_t)(n0 + row) * 512 + ko],       &Bhs[w * 8]);
            gload16(&BpT[(size_t)(n0 + row) * 512 + 256 + ko], &Bls[w * 8]);
        }
        __syncthreads();

        s16x8 ah[4], al[4], bh[4], bl_[4];
#pragma unroll
        for (int i = 0; i < 4; ++i) {
            const int ar  = wr * 64 + i * 16 + lr;
            const int aof = ar * 32 + ((lk ^ (ar & 3) ^ ((ar >> 2) & 3)) << 3);
            ah[i] = *(const s16x8*)&Ahs[aof];
            al[i] = *(const s16x8*)&Als[aof];
            const int brw = wc * 64 + i * 16 + lr;
            const int bof = brw * 32 + ((lk ^ (brw & 3) ^ ((brw >> 2) & 3)) << 3);
            bh[i]  = *(const s16x8*)&Bhs[bof];
            bl_[i] = *(const s16x8*)&Bls[bof];
        }
#pragma unroll
        for (int i = 0; i < 4; ++i)
#pragma unroll
            for (int j = 0; j < 4; ++j) {
                acc[i][j] = __builtin_amdgcn_mfma_f32_16x16x32_bf16(ah[i], bh[j],  acc[i][j], 0, 0, 0);
                acc[i][j] = __builtin_amdgcn_mfma_f32_16x16x32_bf16(ah[i], bl_[j], acc[i][j], 0, 0, 0);
                acc[i][j] = __builtin_amdgcn_mfma_f32_16x16x32_bf16(al[i], bh[j],  acc[i][j], 0, 0, 0);
            }
    }

    float* const outp = (n0 < 512) ? xl : xr;
    const int ocol0 = n0 & 511;
    const float* const bb = (n0 < 512) ? bl : br;
#pragma unroll
    for (int j = 0; j < 4; ++j) {
        const int col = ocol0 + wc * 64 + j * 16 + lr;
        const float bv = bb[col];
#pragma unroll
        for (int i = 0; i < 4; ++i) {
#pragma unroll
            for (int r = 0; r < 4; ++r) {
                const int rowg = m0 + wr * 64 + i * 16 + lk * 4 + r;
                outp[(size_t)rowg * 512 + col] = acc[i][j][r] + bv;
            }
        }
    }
}

// ---------------------------------------------------------------------------
// Counting sort of edges by dst
// ---------------------------------------------------------------------------
__global__ void k_hist(const int* __restrict__ ei, int* __restrict__ counts)
{
    int e = blockIdx.x * 256 + threadIdx.x;
    if (e < N_EDGES) atomicAdd(&counts[ei[N_EDGES + e]], 1);
}

__global__ __launch_bounds__(1024) void k_scan(
    const int* __restrict__ counts, int* __restrict__ offsets, int* __restrict__ cursors)
{
    __shared__ int part[1024];
    const int tid = threadIdx.x;
    const int base = tid * 32;
    int loc[32];
    int s = 0;
#pragma unroll
    for (int i = 0; i < 32; ++i) { loc[i] = s; s += counts[base + i]; }
    part[tid] = s;
    __syncthreads();
    const int own = s;
    for (int off = 1; off < 1024; off <<= 1) {
        int v = (tid >= off) ? part[tid - off] : 0;
        __syncthreads();
        part[tid] += v;
        __syncthreads();
    }
    const int pre = part[tid] - own;   // exclusive prefix of chunk
#pragma unroll
    for (int i = 0; i < 32; ++i) {
        int o = pre + loc[i];
        offsets[base + i] = o;
        cursors[base + i] = o;
    }
}

__global__ void k_scatter(const int* __restrict__ ei, int* __restrict__ cursors,
                          int* __restrict__ sorted_src, int* __restrict__ sorted_dst,
                          int* __restrict__ sorted_eid)
{
    int e = blockIdx.x * 256 + threadIdx.x;
    if (e >= N_EDGES) return;
    int d = ei[N_EDGES + e];
    int pos = atomicAdd(&cursors[d], 1);
    sorted_src[pos] = ei[e];
    sorted_dst[pos] = d;
    sorted_eid[pos] = e;
}

// ---------------------------------------------------------------------------
// k_edge_fused: logits + softmax + aggregation in one pass.
// Grid = (N/32) x 4 slabs; block = 4 waves; each WAVE owns DPW=8 consecutive
// dsts (no barriers -> no divergence hazard). Per 16-edge chunk of a dst:
//   afr   : direct global 16B/lane from eabf (contiguous per wave)
//   bfr[8]: We channel-fragments, loop-invariant in 32 VGPRs
//   1 MFMA per head-quadrant -> edot; gather xl[src] (masked), xr[dst] hoisted
//   per dst; lrelu; att-dot; 16-lane reduce -> per-edge logits (2 heads);
//   wave-uniform online softmax; weighted accumulate of xlv.
// End of dst: reduce partials over lk groups (shfl 16,32), h=relu(acc/den+b).
// ---------------------------------------------------------------------------
#define DPW 8

__global__ __launch_bounds__(256, 4) void k_edge_fused(
    const float* __restrict__ xl, const float* __restrict__ xr,
    const u16* __restrict__ eabf, const u16* __restrict__ webf,
    const float* __restrict__ att, const float* __restrict__ bias,
    const int* __restrict__ offsets, const int* __restrict__ counts,
    const int* __restrict__ sorted_src,
    float* __restrict__ h)
{
    const int tid  = threadIdx.x;
    const int lane = tid & 63;
    const int wid  = tid >> 6;
    const int slab = blockIdx.y;                 // 0..3
    const int lr   = lane & 15;
    const int lk   = lane >> 4;
    const int chbase = slab * 128 + lr;

    // Loop-invariant B fragments (channel rows of We^T) + att weights.
    s16x8 bfr[8];
#pragma unroll
    for (int f = 0; f < 8; ++f)
        bfr[f] = *(const s16x8*)&webf[(size_t)slab * 4096 + (f * 16 + lr) * 32 + lk * 8];
    float attw[8];
#pragma unroll
    for (int f = 0; f < 8; ++f) attw[f] = att[slab * 128 + f * 16 + lr];

    for (int dd = 0; dd < DPW; ++dd) {
        const int d   = (blockIdx.x * 4 + wid) * DPW + dd;
        const int off = offsets[d];
        const int deg = counts[d];

        // xr row hoisted once per dst.
        float xrv[8];
#pragma unroll
        for (int f = 0; f < 8; ++f)
            xrv[f] = xr[(size_t)d * 512 + chbase + f * 16];

        float m0 = -INFINITY, m1 = -INFINITY, den0 = 0.f, den1 = 0.f;
        float accO[8];
#pragma unroll
        for (int f = 0; f < 8; ++f) accO[f] = 0.f;

        for (int base = 0; base < deg; base += 16) {
            // A fragment: edge row lr, k-chunk lk (fully coalesced 1KB/wave).
            const s16x8 afr = *(const s16x8*)&eabf[(size_t)(off + base + lr) * 32 + lk * 8];

            int srcv[4];
#pragma unroll
            for (int r = 0; r < 4; ++r) {
                const int el = lk * 4 + r;
                srcv[r] = (base + el < deg) ? sorted_src[off + base + el] : -1;
            }
            // gather xl rows (masked); kept for the weighted accumulate.
            float xlv[4][8];
#pragma unroll
            for (int r = 0; r < 4; ++r) {
                if (srcv[r] >= 0) {
                    const size_t sb = (size_t)srcv[r] * 512 + chbase;
#pragma unroll
                    for (int f = 0; f < 8; ++f) xlv[r][f] = xl[sb + f * 16];
                } else {
#pragma unroll
                    for (int f = 0; f < 8; ++f) xlv[r][f] = 0.f;
                }
            }

            float p0[4] = {0.f, 0.f, 0.f, 0.f}, p1[4] = {0.f, 0.f, 0.f, 0.f};
#pragma unroll
            for (int f = 0; f < 8; ++f) {
                const f32x4 ef = __builtin_amdgcn_mfma_f32_16x16x32_bf16(
                    afr, bfr[f], (f32x4){0.f, 0.f, 0.f, 0.f}, 0, 0, 0);
#pragma unroll
                for (int r = 0; r < 4; ++r) {
                    float z = ef[r] + xlv[r][f] + xrv[f];
                    z = z > 0.f ? z : NEG * z;
                    if (f < 4) p0[r] += attw[f] * z;
                    else       p1[r] += attw[f] * z;
                }
            }
            // 16-lane (lr) reduce -> logits of the lane's 4 edges, both heads.
#pragma unroll
            for (int o = 1; o < 16; o <<= 1) {
#pragma unroll
                for (int r = 0; r < 4; ++r) {
                    p0[r] += __shfl_xor(p0[r], o);
                    p1[r] += __shfl_xor(p1[r], o);
                }
            }
#pragma unroll
            for (int r = 0; r < 4; ++r) {
                if (base + lk * 4 + r >= deg) { p0[r] = -INFINITY; p1[r] = -INFINITY; }
            }
            // chunk max per head (wave-uniform).
            float c0 = fmaxf(fmaxf(p0[0], p0[1]), fmaxf(p0[2], p0[3]));
            float c1 = fmaxf(fmaxf(p1[0], p1[1]), fmaxf(p1[2], p1[3]));
            c0 = fmaxf(c0, __shfl_xor(c0, 16)); c0 = fmaxf(c0, __shfl_xor(c0, 32));
            c1 = fmaxf(c1, __shfl_xor(c1, 16)); c1 = fmaxf(c1, __shfl_xor(c1, 32));
            const float mn0 = fmaxf(m0, c0), mn1 = fmaxf(m1, c1);
            const float s0 = __expf(m0 - mn0), s1 = __expf(m1 - mn1);
            float w0[4], w1[4];
#pragma unroll
            for (int r = 0; r < 4; ++r) {
                w0[r] = __expf(p0[r] - mn0);
                w1[r] = __expf(p1[r] - mn1);
            }
            den0 = den0 * s0 + w0[0] + w0[1] + w0[2] + w0[3];
            den1 = den1 * s1 + w1[0] + w1[1] + w1[2] + w1[3];
#pragma unroll
            for (int f = 0; f < 8; ++f) {
                float a = accO[f] * ((f < 4) ? s0 : s1);
#pragma unroll
                for (int r = 0; r < 4; ++r)
                    a += ((f < 4) ? w0[r] : w1[r]) * xlv[r][f];
                accO[f] = a;
            }
            m0 = mn0; m1 = mn1;
        }

        // reduce partials across the 4 lk groups.
#pragma unroll
        for (int o = 16; o < 64; o <<= 1) {
            den0 += __shfl_xor(den0, o);
            den1 += __shfl_xor(den1, o);
#pragma unroll
            for (int f = 0; f < 8; ++f) accO[f] += __shfl_xor(accO[f], o);
        }
        const float r0 = den0 > 0.f ? 1.f / den0 : 0.f;
        const float r1 = den1 > 0.f ? 1.f / den1 : 0.f;
        if (lk == 0) {
#pragma unroll
            for (int f = 0; f < 8; ++f) {
                const float hv = fmaxf(accO[f] * ((f < 4) ? r0 : r1) + bias[chbase + f * 16], 0.f);
                h[(size_t)d * 512 + chbase + f * 16] = hv;
            }
        }
    }
}

// ---------------------------------------------------------------------------
// k_score: score[n] = tanh(h[n].pw / ||pw||). One wave per node.
// ---------------------------------------------------------------------------
__global__ __launch_bounds__(256) void k_score(
    const float* __restrict__ h, const float* __restrict__ pw,
    float* __restrict__ score)
{
    const int lane = threadIdx.x & 63;
    const int wv   = threadIdx.x >> 6;
    const int n    = blockIdx.x * 4 + wv;
    const float4 a = *(const float4*)&pw[lane * 8];
    const float4 b = *(const float4*)&pw[lane * 8 + 4];
    float nrm = a.x*a.x + a.y*a.y + a.z*a.z + a.w*a.w
              + b.x*b.x + b.y*b.y + b.z*b.z + b.w*b.w;
    const float4 c  = *(const float4*)&h[(size_t)n * 512 + lane * 8];
    const float4 d4 = *(const float4*)&h[(size_t)n * 512 + lane * 8 + 4];
    float dot = a.x*c.x + a.y*c.y + a.z*c.z + a.w*c.w
              + b.x*d4.x + b.y*d4.y + b.z*d4.z + b.w*d4.w;
#pragma unroll
    for (int o = 1; o < 64; o <<= 1) {
        nrm += __shfl_xor(nrm, o);
        dot += __shfl_xor(dot, o);
    }
    if (lane == 0) score[n] = tanhf(dot / sqrtf(nrm));
}

// ---------------------------------------------------------------------------
// Per-graph top-K via bitonic sort of packed keys (score desc, idx asc)
// ---------------------------------------------------------------------------
__global__ __launch_bounds__(256) void k_topk(const float* __restrict__ score,
                                              int* __restrict__ sel_idx,
                                              float* __restrict__ sel_val)
{
    __shared__ unsigned long long key[1024];
    const int g = blockIdx.x, tid = threadIdx.x;
    for (int i = tid; i < 1024; i += 256) {
        float s = score[g * 1024 + i];
        unsigned u = __float_as_uint(s);
        u = (u & 0x80000000u) ? ~u : (u | 0x80000000u);   // orderable, ascending
        key[i] = ((unsigned long long)(~u) << 32) | (unsigned)i;  // asc key == desc score
    }
    __syncthreads();
    for (int k = 2; k <= 1024; k <<= 1) {
        for (int j = k >> 1; j > 0; j >>= 1) {
            for (int i = tid; i < 1024; i += 256) {
                int ixj = i ^ j;
                if (ixj > i) {
                    bool up = ((i & k) == 0);
                    unsigned long long a = key[i], b = key[ixj];
                    if ((a > b) == up) { key[i] = b; key[ixj] = a; }
                }
            }
            __syncthreads();
        }
    }
    for (int kk = tid; kk < KSEL; kk += 256) {
        int idx = (int)(key[kk] & 0xFFFFFFFFu);
        sel_idx[g * KSEL + kk] = idx;
        sel_val[g * KSEL + kk] = score[g * 1024 + idx];
    }
}

// ---------------------------------------------------------------------------
// Pool: gmp = max_k(h[idx_k]*val_k), gap = mean_k(...) — k-sliced + merge
// ---------------------------------------------------------------------------
#define KSLICE 103

__global__ __launch_bounds__(256) void k_pool_part(
    const float* __restrict__ h, const int* __restrict__ sel_idx,
    const float* __restrict__ sel_val, float* __restrict__ part)
{
    const int g = blockIdx.x >> 3, sl = blockIdx.x & 7;
    const int kbeg = sl * KSLICE;
    const int kend = min(KSEL, kbeg + KSLICE);
    const int n = kend - kbeg;
    __shared__ float vs[KSLICE];
    __shared__ int   is_[KSLICE];
    const int tid = threadIdx.x;
    if (tid < n) {
        vs[tid]  = sel_val[g * KSEL + kbeg + tid];
        is_[tid] = sel_idx[g * KSEL + kbeg + tid];
    }
    __syncthreads();
    const int c0 = tid, c1 = tid + 256;
    float mx0 = -INFINITY, mx1 = -INFINITY, s0 = 0.f, s1 = 0.f;
    for (int kk = 0; kk < n; ++kk) {
        const float* hp = h + ((size_t)(g * 1024 + is_[kk])) * 512;
        const float v = vs[kk];
        float f0 = hp[c0] * v, f1 = hp[c1] * v;
        mx0 = fmaxf(mx0, f0); s0 += f0;
        mx1 = fmaxf(mx1, f1); s1 += f1;
    }
    const size_t base = ((size_t)blockIdx.x * 2) * 512;
    part[base + c0] = mx0;        part[base + c1] = mx1;
    part[base + 512 + c0] = s0;   part[base + 512 + c1] = s1;
}

__global__ __launch_bounds__(256) void k_pool_merge(
    const float* __restrict__ part, float* __restrict__ out)
{
    const int g = blockIdx.x, tid = threadIdx.x;
    const int c0 = tid, c1 = tid + 256;
    float mx0 = -INFINITY, mx1 = -INFINITY, s0 = 0.f, s1 = 0.f;
    for (int sl = 0; sl < 8; ++sl) {
        const size_t base = ((size_t)(g * 8 + sl) * 2) * 512;
        mx0 = fmaxf(mx0, part[base + c0]); mx1 = fmaxf(mx1, part[base + c1]);
        s0 += part[base + 512 + c0];       s1 += part[base + 512 + c1];
    }
    out[(size_t)g * 1024 + c0] = mx0;
    out[(size_t)g * 1024 + c1] = mx1;
    out[(size_t)g * 1024 + 512 + c0] = s0 * (1.f / KSEL);
    out[(size_t)g * 1024 + 512 + c1] = s1 * (1.f / KSEL);
}

// ---------------------------------------------------------------------------
extern "C" void kernel_launch(void* const* d_in, const int* in_sizes, int n_in,
                              void* d_out, int out_size, void* d_ws, size_t ws_size,
                              hipStream_t stream)
{
    const float* x    = (const float*)d_in[0];
    const float* ea   = (const float*)d_in[1];
    const float* Wl   = (const float*)d_in[2];
    const float* bl   = (const float*)d_in[3];
    const float* Wr   = (const float*)d_in[4];
    const float* br   = (const float*)d_in[5];
    const float* We   = (const float*)d_in[6];
    const float* att  = (const float*)d_in[7];
    const float* bias = (const float*)d_in[8];
    const float* pw   = (const float*)d_in[9];
    const int*   ei   = (const int*)d_in[10];
    float* out = (float*)d_out;

    // workspace layout (4B units unless noted)
    float* xl        = (float*)d_ws;                      // N*512
    float* xr        = xl + (size_t)N_NODES * 512;
    float* h         = xr + (size_t)N_NODES * 512;
    float* sel_val   = h + (size_t)N_NODES * 512;         // 32*820
    float* part      = sel_val + BGRAPH * KSEL;           // 256*2*512
    float* score     = part + 256 * 2 * 512;              // 32768
    int* counts      = (int*)(score + N_NODES);
    int* offsets     = counts + N_NODES;
    int* cursors     = offsets + N_NODES;
    int* sorted_src  = cursors + N_NODES;                 // E
    int* sorted_dst  = sorted_src + N_EDGES;              // E
    int* sorted_eid  = sorted_dst + N_EDGES;              // E
    int* sel_idx     = sorted_eid + N_EDGES;              // 32*820
    u16* xhi         = (u16*)(sel_idx + BGRAPH * KSEL);   // N*256 u16
    u16* xlo         = xhi + (size_t)N_NODES * 256;       // N*256 u16
    u16* bpt         = xlo + (size_t)N_NODES * 256;       // 1024*512 u16
    u16* webf        = bpt + (size_t)1024 * 512;          // 4*128*32 u16
    u16* eabf        = webf + 4 * 128 * 32;               // (E+16)*32 u16

    hipMemsetAsync(counts, 0, (size_t)N_NODES * sizeof(int), stream);

    k_split_x<<<(N_NODES * 256) / (4 * 256), 256, 0, stream>>>(x, xhi, xlo);
    k_pack_bt<<<dim3(2, 1024), 256, 0, stream>>>(Wl, Wr, bpt);
    k_prep_we<<<64, 256, 0, stream>>>(We, webf);
    gemm_mfma<<<2048, 256, 0, stream>>>(xhi, xlo, bpt, bl, br, xl, xr);

    k_hist<<<N_EDGES / 256, 256, 0, stream>>>(ei, counts);
    k_scan<<<1, 1024, 0, stream>>>(counts, offsets, cursors);
    k_scatter<<<N_EDGES / 256, 256, 0, stream>>>(ei, cursors, sorted_src, sorted_dst, sorted_eid);
    k_prep_ea<<<(N_EDGES * 32) / 256, 256, 0, stream>>>(ea, sorted_eid, eabf);
    k_edge_fused<<<dim3(N_NODES / (4 * DPW), 4), 256, 0, stream>>>(
        xl, xr, eabf, webf, att, bias, offsets, counts, sorted_src, h);
    k_score<<<N_NODES / 4, 256, 0, stream>>>(h, pw, score);
    k_topk<<<BGRAPH, 256, 0, stream>>>(score, sel_idx, sel_val);
    k_pool_part<<<BGRAPH * 8, 256, 0, stream>>>(h, sel_idx, sel_val, part);
    k_pool_merge<<<BGRAPH, 256, 0, stream>>>(part, out);
}